// Round 14
// baseline (2444.255 us; speedup 1.0000x reference)
//
#include <hip/hip_runtime.h>
#include <hip/hip_bf16.h>
#include <stdint.h>

// Persistent-RNN, R18: de-confounded P=8 topology test.
//  - 64 blocks x 512 threads (8 waves). 8 chains (batch groups) x 8 col-blocks.
//  - Block (g,p): g = blockIdx&7 (chain==XCD under round-robin; all 8 blocks of
//    a chain land on ONE XCD), p = blockIdx>>3. Rows [16g,16g+16), cols
//    [128p,128p+128).
//  - R6 tested this geometry but bundled two independent regressions: sc1-only
//    polling under concentration (the proven R6/R12 funnel, ~+300us) and a
//    probable VGPR-spill from __launch_bounds__(512,2) (WRITE_SIZE +240MB).
//    R18 removes both: plateau poll regime (R10/R17: dual-buffer, 1:1 sc0/sc1
//    serial sweeps, dual fire-and-forget store, mirror readout) and
//    __launch_bounds__(512,1) (VGPR cap 512; only 64 CUs used so occupancy
//    is irrelevant for this latency-bound kernel).
//  - Hypothesis: step completion is gated by max over P producers (+poll
//    volume ~ P). P=16 plateau at ~3.37us/step; P=8 -> fewer stragglers, one
//    producer per consumer wave, half the sweep traffic.
//  - Datapath: hi-only bf16 weights (whh[8][4] = 128 VGPR), FULL hi+lo state,
//    products (s_hi+s_lo)*W_hi -- R6-verified numerics, absmax 0.0039.
//  - Tag protocol unchanged: u32 = (bf16hi<<16)|(bf16lo&~1|parity); all 32
//    tags/lane must equal (t>>1)&1; passing sweep IS the state load; stale
//    words carry the opposite tag -> never false-pass.
//  - WAR safety: fresh word from producer B implies B passed its step-(t-1)
//    block barrier implies all B's step-(t-1) reads retired (in regs).

#define TSTEPS 512
#define BATCH  128
#define NI     256
#define NH     1024
#define NO     128
#define NBLK   64
#define NTHR   512
#define NWAVE  8
#define BG     16
#define COLS   128
#define SPBUF  ((size_t)BATCH * NH)          // u32s per state buffer (2^17)

typedef __attribute__((ext_vector_type(8))) short s16x8;
typedef __attribute__((ext_vector_type(4))) float f32x4;
typedef __attribute__((ext_vector_type(4))) unsigned u32x4;
typedef unsigned long long ull;

__device__ __forceinline__ unsigned short f2bf_rne(float f) {
  unsigned u = __builtin_bit_cast(unsigned, f);
  unsigned r = u + 0x7fffu + ((u >> 16) & 1u);
  return (unsigned short)(r >> 16);
}
__device__ __forceinline__ float bf2f(unsigned short h) {
  unsigned u = ((unsigned)h) << 16;
  return __builtin_bit_cast(float, u);
}
__device__ __forceinline__ void split_bf(float v, short &hi, short &lo) {
  unsigned short h = f2bf_rne(v);
  hi = (short)h;
  lo = (short)f2bf_rne(v - bf2f(h));
}
__device__ __forceinline__ f32x4 mfma16(s16x8 a, s16x8 b, f32x4 c) {
  return __builtin_amdgcn_mfma_f32_16x16x32_bf16(a, b, c, 0, 0, 0);
}
__device__ __forceinline__ float fast_tanh(float a) {
  float cl = fminf(fmaxf(a, -15.f), 15.f);
  float e  = __expf(2.f * cl);
  return (e - 1.f) / (e + 1.f);
}

// state u32 index: [g 0..8)[slice 0..8)[r 0..16)[k_local 0..128)
//   hidden col = slice*128 + k_local ; batch row = g*16 + r
//   slice p is written by producer block (g,p), polled by wave p of consumers.
#define SIDX(g, p, r, k) ((((size_t)(g) * NWAVE + (p)) * BG + (r)) * 128 + (k))

__global__ __launch_bounds__(NTHR, 1)
void rnn_persistent(const float* __restrict__ x,
                    const float* __restrict__ W_ih,
                    const float* __restrict__ W_hh,
                    const float* __restrict__ b_ih,
                    const float* __restrict__ b_hh,
                    unsigned*    __restrict__ SP)    // [4][128][1024]: L2buf0,L2buf1,MIR0,MIR1
{
  const int tid  = threadIdx.x;
  const int wave = tid >> 6;
  const int lane = tid & 63;
  const int lr   = lane & 15;
  const int lq   = lane >> 4;
  const int g    = blockIdx.x & 7;     // chain == XCD (round-robin, proven R8)
  const int p    = blockIdx.x >> 3;    // 8 col-partitions per chain
  const int row0 = g * BG;
  const int h0   = p * COLS;
  const int kq0  = wave * 128;         // this wave's hidden-K slice (== slice 'wave')
  const int iq0  = wave * 32;          // this wave's input-K slice

  __shared__ float red[NWAVE][BG][COLS];   // 64 KB, single-buffered (2 barriers/step)

  // ---- persistent W_hh B-fragments, HI-ONLY: [n-tile 0..7][kb 0..3] ----
  // B[k][n] = W_hh[h0+n][k]; lane holds n = lane&15, k = kq0+kb*32+quad*8+j.
  s16x8 whh[8][4];
  #pragma unroll
  for (int nt = 0; nt < 8; ++nt) {
    const int h = h0 + nt * 16 + lr;
    #pragma unroll
    for (int kb = 0; kb < 4; ++kb) {
      const float* pw = W_hh + (size_t)h * NH + kq0 + kb * 32 + lq * 8;
      s16x8 hi;
      #pragma unroll
      for (int j = 0; j < 8; ++j) hi[j] = (short)f2bf_rne(pw[j]);
      whh[nt][kb] = hi;
    }
  }
  // ---- persistent W_ih B-fragments, HI-ONLY: [n-tile 0..7], 32-wide k ----
  s16x8 wih[8];
  #pragma unroll
  for (int nt = 0; nt < 8; ++nt) {
    const int h = h0 + nt * 16 + lr;
    const float* pw = W_ih + (size_t)h * NI + iq0 + lq * 8;
    s16x8 hi;
    #pragma unroll
    for (int j = 0; j < 8; ++j) hi[j] = (short)f2bf_rne(pw[j]);
    wih[nt] = hi;
  }

  // epilogue ownership: thread -> row tid>>5, cols 4*(tid&31) .. +3
  const int er = tid >> 5;
  const int ec = (tid & 31) * 4;
  float bias[4];
  #pragma unroll
  for (int j = 0; j < 4; ++j) bias[j] = b_ih[h0 + ec + j] + b_hh[h0 + ec + j];

  unsigned* lb0 = SP;                  // L2-scope double buffer
  unsigned* lb1 = SP + SPBUF;
  unsigned* mr0 = SP + 2 * SPBUF;      // IC mirror double buffer
  unsigned* mr1 = SP + 3 * SPBUF;

  // x prefetch registers (step 0)
  float xf[8];
  {
    const float* xp = x + (size_t)(row0 + lr) * NI + iq0 + lq * 8;
    #pragma unroll
    for (int j = 0; j < 8; ++j) xf[j] = xp[j];
  }

  // consumer poll bases: wave 'wave' polls slice 'wave' (producer block (g,wave))
  const size_t soff = SIDX(g, wave, lr, lq * 8);
  const unsigned* sbL[2] = { lb0 + soff, lb1 + soff };
  const unsigned* sbM[2] = { mr0 + soff, mr1 + soff };
  // producer store offset (slice p, this thread's 4 cols)
  const size_t poff = SIDX(g, p, er, ec);

  for (int t = 0; t < TSTEPS; ++t) {
    // ---------- x projection from prefetched registers (2-product, hi-only W) ----------
    f32x4 acc[8];
    #pragma unroll
    for (int nt = 0; nt < 8; ++nt) acc[nt] = (f32x4){0.f, 0.f, 0.f, 0.f};
    {
      s16x8 xhi, xlo;
      #pragma unroll
      for (int j = 0; j < 8; ++j) { short a, b; split_bf(xf[j], a, b); xhi[j] = a; xlo[j] = b; }
      #pragma unroll
      for (int nt = 0; nt < 8; ++nt) {
        acc[nt] = mfma16(xhi, wih[nt], acc[nt]);
        acc[nt] = mfma16(xlo, wih[nt], acc[nt]);
      }
    }
    // ---------- poll: alternate sc0 sweep (L2 fast path) / sc1 sweep (IC truth) ----------
    const unsigned etag = (unsigned)((t >> 1) & 1);
    const unsigned* sb = sbL[t & 1];
    const unsigned* mb = sbM[t & 1];
    u32x4 sv0, sv1, sv2, sv3, sv4, sv5, sv6, sv7;
    {
      const u32x4 e4 = (u32x4){etag, etag, etag, etag};
      for (;;) {
        // L2 fast path: sc0 (SE scope)
        asm volatile(
          "global_load_dwordx4 %0, %8, off sc0\n\t"
          "global_load_dwordx4 %1, %8, off offset:16 sc0\n\t"
          "global_load_dwordx4 %2, %8, off offset:128 sc0\n\t"
          "global_load_dwordx4 %3, %8, off offset:144 sc0\n\t"
          "global_load_dwordx4 %4, %8, off offset:256 sc0\n\t"
          "global_load_dwordx4 %5, %8, off offset:272 sc0\n\t"
          "global_load_dwordx4 %6, %8, off offset:384 sc0\n\t"
          "global_load_dwordx4 %7, %8, off offset:400 sc0\n\t"
          "s_waitcnt vmcnt(0)"
          : "=&v"(sv0), "=&v"(sv1), "=&v"(sv2), "=&v"(sv3),
            "=&v"(sv4), "=&v"(sv5), "=&v"(sv6), "=&v"(sv7)
          : "v"(sb) : "memory");
        {
          u32x4 b4 = (sv0 ^ e4) | (sv1 ^ e4) | (sv2 ^ e4) | (sv3 ^ e4)
                   | (sv4 ^ e4) | (sv5 ^ e4) | (sv6 ^ e4) | (sv7 ^ e4);
          unsigned bad = b4[0] | b4[1] | b4[2] | b4[3];
          if ((bad & 1u) == 0) break;
        }
        // IC truth path (liveness regardless of placement/scope semantics)
        asm volatile(
          "global_load_dwordx4 %0, %8, off sc1\n\t"
          "global_load_dwordx4 %1, %8, off offset:16 sc1\n\t"
          "global_load_dwordx4 %2, %8, off offset:128 sc1\n\t"
          "global_load_dwordx4 %3, %8, off offset:144 sc1\n\t"
          "global_load_dwordx4 %4, %8, off offset:256 sc1\n\t"
          "global_load_dwordx4 %5, %8, off offset:272 sc1\n\t"
          "global_load_dwordx4 %6, %8, off offset:384 sc1\n\t"
          "global_load_dwordx4 %7, %8, off offset:400 sc1\n\t"
          "s_waitcnt vmcnt(0)"
          : "=&v"(sv0), "=&v"(sv1), "=&v"(sv2), "=&v"(sv3),
            "=&v"(sv4), "=&v"(sv5), "=&v"(sv6), "=&v"(sv7)
          : "v"(mb) : "memory");
        {
          u32x4 b4 = (sv0 ^ e4) | (sv1 ^ e4) | (sv2 ^ e4) | (sv3 ^ e4)
                   | (sv4 ^ e4) | (sv5 ^ e4) | (sv6 ^ e4) | (sv7 ^ e4);
          unsigned bad = b4[0] | b4[1] | b4[2] | b4[3];
          if ((bad & 1u) == 0) break;
        }
      }
    }
    // ---------- prefetch x[t+1] (hides HBM latency under MFMA + epilogue) ----------
    {
      const int tn = (t + 1 < TSTEPS) ? (t + 1) : t;
      const float* xp = x + (size_t)tn * BATCH * NI + (size_t)(row0 + lr) * NI + iq0 + lq * 8;
      #pragma unroll
      for (int j = 0; j < 8; ++j) xf[j] = xp[j];
    }
    // ---------- recurrent MFMAs: (s_hi + s_lo) x W_hi, per 32-wide kb ----------
    #pragma unroll
    for (int kb = 0; kb < 4; ++kb) {
      const u32x4 va = (kb == 0) ? sv0 : (kb == 1) ? sv2 : (kb == 2) ? sv4 : sv6;
      const u32x4 vb = (kb == 0) ? sv1 : (kb == 1) ? sv3 : (kb == 2) ? sv5 : sv7;
      s16x8 shi, slo;
      #pragma unroll
      for (int i = 0; i < 4; ++i) {
        unsigned wa = va[i], wb = vb[i];
        shi[i]     = (short)(wa >> 16); slo[i]     = (short)(wa & 0xffffu);
        shi[i + 4] = (short)(wb >> 16); slo[i + 4] = (short)(wb & 0xffffu);
      }
      #pragma unroll
      for (int nt = 0; nt < 8; ++nt) {
        acc[nt] = mfma16(shi, whh[nt][kb], acc[nt]);
        acc[nt] = mfma16(slo, whh[nt][kb], acc[nt]);
      }
    }
    // ---------- cross-wave K reduction (single-buffered -> 2 barriers/step) ----------
    // C/D layout: col = lane&15, row = quad*4 + reg (m89/m91 verified)
    __syncthreads();   // B1: previous step's epilogue reads of red are done
    #pragma unroll
    for (int nt = 0; nt < 8; ++nt)
      #pragma unroll
      for (int r = 0; r < 4; ++r)
        red[wave][lq * 4 + r][nt * 16 + lr] = acc[nt][r];
    __syncthreads();   // B2: all partials visible
    // ---------- epilogue: reduce 8 waves, tanh, dual tagged store (fire, no drain) ----------
    {
      float s[4] = {bias[0], bias[1], bias[2], bias[3]};
      #pragma unroll
      for (int w = 0; w < NWAVE; ++w) {
        const f32x4 v = *(const f32x4*)&red[w][er][ec];
        s[0] += v[0]; s[1] += v[1]; s[2] += v[2]; s[3] += v[3];
      }
      const unsigned otag = (unsigned)(((t + 1) >> 1) & 1);
      u32x4 pkw;
      #pragma unroll
      for (int j = 0; j < 4; ++j) {
        float tv = fast_tanh(s[j]);
        unsigned short hb = f2bf_rne(tv);
        unsigned       lb = ((f2bf_rne(tv - bf2f(hb)) & 0xfffeu) | otag);
        pkw[j] = (((unsigned)hb) << 16) | lb;
      }
      unsigned* lbd = ((t + 1) & 1) ? lb1 : lb0;
      unsigned* mrd = ((t + 1) & 1) ? mr1 : mr0;
      unsigned* opL = lbd + poff;
      unsigned* opM = mrd + poff;
      // (a) sc0 store -> SE scope: write-through past L1 into this XCD's L2
      asm volatile("global_store_dwordx4 %0, %1, off sc0" :: "v"(opL), "v"(pkw) : "memory");
      // (b) sc1 store -> IC/HBM coherence point: liveness truth + readout source
      asm volatile("global_store_dwordx4 %0, %1, off sc1" :: "v"(opM), "v"(pkw) : "memory");
    }
  }
}

__global__ __launch_bounds__(256)
void init_sp(unsigned* __restrict__ SP) {
  // regions: [0]=L2 buf0 (tag0 zeros), [1]=L2 buf1 (stale tag1),
  //          [2]=MIR buf0 (tag0 zeros), [3]=MIR buf1 (stale tag1)
  const size_t i = (size_t)blockIdx.x * 256 + threadIdx.x;
  SP[i] = (unsigned)((i >> 17) & 1);   // SPBUF = 2^17
}

__global__ __launch_bounds__(512)
void rnn_readout(const unsigned* __restrict__ SP,      // reads MIRROR buf0 (T even; sc1-visible)
                 const float* __restrict__ W_ro,       // [128][1024]
                 const float* __restrict__ b_ro,       // [128]
                 float* __restrict__ out)              // [128][128]
{
  __shared__ float srow[4][NH];
  const unsigned* MIR0 = SP + 2 * SPBUF;
  const int b0 = blockIdx.x * 4;
  for (int i = threadIdx.x; i < 4 * NH; i += 512) {
    const int b = b0 + (i >> 10);
    const int h = i & 1023;
    unsigned u = MIR0[SIDX(b >> 4, h >> 7, b & 15, h & 127)];
    srow[i >> 10][h] = bf2f((unsigned short)(u >> 16)) + bf2f((unsigned short)(u & 0xfffeu));
  }
  __syncthreads();
  const int bb = threadIdx.x >> 7;
  const int o  = threadIdx.x & 127;
  const float* wr = W_ro + (size_t)o * NH;
  float s = 0.f;
  #pragma unroll 4
  for (int k = 0; k < NH; ++k) s += srow[bb][k] * wr[k];
  out[(size_t)(b0 + bb) * NO + o] = s + b_ro[o];
}

extern "C" void kernel_launch(void* const* d_in, const int* in_sizes, int n_in,
                              void* d_out, int out_size, void* d_ws, size_t ws_size,
                              hipStream_t stream) {
  (void)in_sizes; (void)n_in; (void)out_size; (void)ws_size;
  const float* x    = (const float*)d_in[0];
  const float* W_ih = (const float*)d_in[1];
  const float* W_hh = (const float*)d_in[2];
  const float* b_ih = (const float*)d_in[3];
  const float* b_hh = (const float*)d_in[4];
  const float* W_ro = (const float*)d_in[5];
  const float* b_ro = (const float*)d_in[6];
  float* out = (float*)d_out;

  unsigned* SP = (unsigned*)d_ws;   // [4][128][1024] u32 = 2 MB

  init_sp<<<(4 * BATCH * NH) / 256, 256, 0, stream>>>(SP);

  rnn_persistent<<<NBLK, NTHR, 0, stream>>>(x, W_ih, W_hh, b_ih, b_hh, SP);
  // T=512 even -> final state in buf0 (mirror copy, sc1-visible post-kernel)
  rnn_readout<<<BATCH / 4, 512, 0, stream>>>(SP, W_ro, b_ro, out);
}